// Round 10
// baseline (61.423 us; speedup 1.0000x reference)
//
#include <hip/hip_runtime.h>
#include <math.h>

#define EMB 128
#define WIN 200
#define NT 64
#define BB 128

typedef short bf16x8 __attribute__((ext_vector_type(8)));
typedef float f32x4  __attribute__((ext_vector_type(4)));

__device__ __forceinline__ ushort bf16r(float x) {                 // RNE round
    unsigned u = __float_as_uint(x);
    return (ushort)((u + 0x7FFFu + ((u >> 16) & 1u)) >> 16);
}
__device__ __forceinline__ unsigned pk2bf16(float a, float b) {    // a=lo, b=hi
    unsigned ua = __float_as_uint(a), ub = __float_as_uint(b);
    ua = (ua + 0x7FFFu + ((ua >> 16) & 1u)) >> 16;
    ub = (ub + 0x7FFFu + ((ub >> 16) & 1u)) >> 16;
    return ua | (ub << 16);
}
__device__ __forceinline__ float bf_lo(unsigned u) { return __uint_as_float(u << 16); }
__device__ __forceinline__ float bf_hi(unsigned u) { return __uint_as_float(u & 0xFFFF0000u); }
__device__ __forceinline__ float rdlane(float v, int l) {
    return __uint_as_float(__builtin_amdgcn_readlane(__float_as_uint(v), l));
}

// ---------------------------------------------------------------------------
// prep: block 0 = mask-storage detect (bool-1B vs int32; 6400 int32 = 25600 B
// is safe under both layouts). blocks 1..128: W_w row n -> bf16 Wb16[n][e],
// e in [0,256) — the B^T ([n][k]) layout MFMA wants.
// ---------------------------------------------------------------------------
__global__ void prep_kernel(const float* __restrict__ Ww, ushort* __restrict__ Wb16,
                            const int* __restrict__ mi, int* __restrict__ flag) {
    if (blockIdx.x == 0) {
        __shared__ int s;
        if (threadIdx.x == 0) s = 0;
        __syncthreads();
        int bad = 0;
        for (int i = threadIdx.x; i < 6400; i += blockDim.x)
            if ((unsigned)mi[i] > 1u) bad = 1;
        if (bad) s = 1;
        __syncthreads();
        if (threadIdx.x == 0) flag[0] = s;
    } else {
        int n = blockIdx.x - 1;
        int e = threadIdx.x;
        Wb16[n * 256 + e] = bf16r(Ww[n * 256 + e]);
    }
}

// ---------------------------------------------------------------------------
// FUSED kernel: one block per (b, 32-t half). 512 thr = 8 waves x 4 t.
// Phase A: stage s_ci/s_hw/s_bias/s_B(Wq); wave0 mask-compaction.
// Phase B: stage A-tiles (200 cvecs rows + 32 tvecs rows, bf16, XOR-swizzled).
// Phase C: hq = k-row @ Wq^T via MFMA (13 frags / 8 waves), +bias, bf16 ->
//          s_hq[nc][w][4] (score layout).
// Phase D: restage s_B = Wp.   Phase E: hp MFMA (16 subjobs) -> s_hp[t][n].
// Phase F: score (bf16 unpack) -> reg softmax -> PV direct from L2 -> out.
// Frag code identical to round-9-verified proj (A/B row XOR-swizzle ^row&7;
// C map col=lane&15, row=(lane>>4)*4+reg). LDS ~157 KB -> 1 block/CU.
// ---------------------------------------------------------------------------
__global__ __launch_bounds__(512, 2) void attn_kernel(
    const float* __restrict__ tvecs, const float* __restrict__ cvecs,
    const ushort* __restrict__ Wb16, const float* __restrict__ Wbias,
    const float* __restrict__ hwg,
    const int* __restrict__ titems, const int* __restrict__ citems,
    const void* __restrict__ mask_raw, const int* __restrict__ flagp,
    float* __restrict__ outp)
{
    __shared__ __align__(16) ushort s_A[240 * 128];   // 61.4 KB: rows 0..207 = w (0..199 valid), 208..239 = t
    __shared__ __align__(16) ushort s_B[128 * 128];   // 32 KB (Wq, then Wp)
    __shared__ __align__(16) ushort s_hq[200 * 128];  // 51.2 KB; ushort idx (nc*200+w)*4 + (col&3)
    __shared__ __align__(16) ushort s_hp[32 * 128];   // 8 KB [t][n]
    __shared__ __align__(16) float  s_hw[128];
    __shared__ float    s_bias[128];
    __shared__ int      s_ci[WIN], s_widx[WIN];
    __shared__ unsigned s_coff[WIN];
    __shared__ int      s_m;

    const int tid  = threadIdx.x;
    const int lane = tid & 63;
    const int wid  = tid >> 6;
    const int b    = blockIdx.x >> 1;
    const int tb   = (blockIdx.x & 1) * 32;
    const int t0   = wid * 4;

    // ---------------- Phase A ----------------
    if (tid < WIN) s_ci[tid] = citems[b * WIN + tid];
    if (tid < 128) { s_hw[tid] = hwg[tid]; s_bias[tid] = Wbias[tid]; }
    for (int i = tid; i < 2048; i += 512) {           // B = Wq (k=128..256)
        int n = i >> 4, j = i & 15;
        uint4 v = *(const uint4*)&Wb16[n * 256 + 128 + 8 * j];
        *(uint4*)((char*)s_B + n * 256 + ((j ^ (n & 7)) << 4)) = v;
    }
    if (wid == 0) {                                   // mask compaction
        const int boolmode = flagp[0];
        const unsigned char* mb = (const unsigned char*)mask_raw;
        const int*           mi = (const int*)mask_raw;
        int base = 0;
#pragma unroll
        for (int r = 0; r < 4; ++r) {
            int w  = r * 64 + lane;
            int mv = 1;
            if (w < WIN) mv = boolmode ? (int)mb[b * WIN + w] : mi[b * WIN + w];
            unsigned long long act = __ballot(mv == 0);
            if (mv == 0)
                s_widx[base + __popcll(act & ((1ull << lane) - 1ull))] = w;
            base += __popcll(act);
        }
        if (lane == 0) s_m = base;
    }
    __syncthreads();

    const int m = s_m;
    const float invn = 1.f / sqrtf(800.f + (float)m);   // 1000 - (200 - m)
    size_t orow = ((size_t)(b * 64 + tb + t0)) * 128;
    if (m == 0) {
#pragma unroll
        for (int j = 0; j < 4; ++j)
            *(float2*)&outp[orow + (size_t)j * 128 + lane * 2] = make_float2(0.f, 0.f);
        return;
    }

    // ---------------- Phase B: A-tiles ----------------
    for (int i = tid; i < 240 * 32; i += 512) {
        int r = i >> 5, j = i & 31;                   // k0 = 4*j
        const float* src = (r < 208)
            ? &cvecs[(size_t)s_ci[min(r, 199)] * 128]
            : &tvecs[(size_t)titems[b * 64 + tb + (r - 208)] * 128];
        float4 v = *(const float4*)&src[4 * j];
        uint2 p; p.x = pk2bf16(v.x, v.y); p.y = pk2bf16(v.z, v.w);
        *(uint2*)((char*)s_A + r * 256 + (((j >> 1) ^ (r & 7)) << 4) + (j & 1) * 8) = p;
    }
    if (tid < m) s_coff[tid] = (unsigned)s_ci[s_widx[tid]] * 512u;
    __syncthreads();

    const int rl = lane & 15, kg = lane >> 4;

    // ---------------- Phase C: hq MFMA (13 frags) ----------------
#pragma unroll
    for (int jj = 0; jj < 2; ++jj) {
        int fb = wid + jj * 8;
        if (fb <= 12) {
            f32x4 acc[8];
#pragma unroll
            for (int i = 0; i < 8; ++i) acc[i] = (f32x4){0.f, 0.f, 0.f, 0.f};
            const int arow = fb * 16 + rl;
#pragma unroll
            for (int s = 0; s < 4; ++s) {
                bf16x8 af = *(const bf16x8*)((const char*)s_A
                              + arow * 256 + ((((s << 2) + kg) ^ (arow & 7)) << 4));
#pragma unroll
                for (int nt = 0; nt < 8; ++nt) {
                    int bn = nt * 16 + rl;
                    bf16x8 bfr = *(const bf16x8*)((const char*)s_B
                                   + bn * 256 + ((((s << 2) + kg) ^ (bn & 7)) << 4));
                    acc[nt] = __builtin_amdgcn_mfma_f32_16x16x32_bf16(af, bfr, acc[nt], 0, 0, 0);
                }
            }
#pragma unroll
            for (int i = 0; i < 4; ++i) {
                int w = fb * 16 + kg * 4 + i;
                if (w < WIN) {
#pragma unroll
                    for (int nt = 0; nt < 8; ++nt) {
                        int col = nt * 16 + rl;
                        s_hq[(((col >> 2) * 200 + w) << 2) + (col & 3)]
                            = bf16r(acc[nt][i] + s_bias[col]);
                    }
                }
            }
        }
    }
    __syncthreads();                                  // hq done; s_B free

    // ---------------- Phase D: restage B = Wp ----------------
    for (int i = tid; i < 2048; i += 512) {
        int n = i >> 4, j = i & 15;
        uint4 v = *(const uint4*)&Wb16[n * 256 + 8 * j];
        *(uint4*)((char*)s_B + n * 256 + ((j ^ (n & 7)) << 4)) = v;
    }
    __syncthreads();

    // ---------------- Phase E: hp MFMA (16 subjobs, 2/wave) ----------------
#pragma unroll
    for (int q = 0; q < 2; ++q) {
        int j2 = wid * 2 + q;                         // 0..15
        int fragId = j2 >> 3, nt = j2 & 7;
        f32x4 acc = (f32x4){0.f, 0.f, 0.f, 0.f};
        const int arow = 208 + fragId * 16 + rl;
        const int bn = nt * 16 + rl;
#pragma unroll
        for (int s = 0; s < 4; ++s) {
            bf16x8 af = *(const bf16x8*)((const char*)s_A
                          + arow * 256 + ((((s << 2) + kg) ^ (arow & 7)) << 4));
            bf16x8 bfr = *(const bf16x8*)((const char*)s_B
                           + bn * 256 + ((((s << 2) + kg) ^ (bn & 7)) << 4));
            acc = __builtin_amdgcn_mfma_f32_16x16x32_bf16(af, bfr, acc, 0, 0, 0);
        }
#pragma unroll
        for (int i = 0; i < 4; ++i) {
            int t = fragId * 16 + kg * 4 + i;
            s_hp[t * 128 + nt * 16 + rl] = bf16r(acc[i]);
        }
    }
    __syncthreads();

    // ---------------- Phase F: score -> softmax -> PV ----------------
    const float4* hw4p = (const float4*)s_hw;
    const char* cvb = (const char*)cvecs;
    const int mc = m - 1;

#define SCS(J, K, HA, HB, HC, HD, PA, PB, PC, PD)                              \
    va[J][K] += hwv.x * fmaxf(HA + PA, 0.f) + hwv.y * fmaxf(HB + PB, 0.f)      \
              + hwv.z * fmaxf(HC + PC, 0.f) + hwv.w * fmaxf(HD + PD, 0.f);

    if (m <= 128) {
        const int wreg0 = s_widx[min(lane, mc)];
        const int wreg1 = s_widx[min(64 + lane, mc)];
        float va[4][2];
#pragma unroll
        for (int j = 0; j < 4; ++j) { va[j][0] = 0.f; va[j][1] = 0.f; }

#pragma unroll 2
        for (int nc = 0; nc < 32; ++nc) {
            uint2 h0 = *(const uint2*)&s_hq[(nc * 200 + wreg0) << 2];
            uint2 h1 = *(const uint2*)&s_hq[(nc * 200 + wreg1) << 2];
            float h0a = bf_lo(h0.x), h0b = bf_hi(h0.x), h0c = bf_lo(h0.y), h0d = bf_hi(h0.y);
            float h1a = bf_lo(h1.x), h1b = bf_hi(h1.x), h1c = bf_lo(h1.y), h1d = bf_hi(h1.y);
            float4 hwv = hw4p[nc];
#pragma unroll
            for (int jt = 0; jt < 4; ++jt) {
                uint2 pu = *(const uint2*)&s_hp[(t0 + jt) * 128 + nc * 4];
                float pa = bf_lo(pu.x), pb = bf_hi(pu.x), pc = bf_lo(pu.y), pd = bf_hi(pu.y);
                SCS(jt, 0, h0a, h0b, h0c, h0d, pa, pb, pc, pd)
                SCS(jt, 1, h1a, h1b, h1c, h1d, pa, pb, pc, pd)
            }
        }

#pragma unroll
        for (int j = 0; j < 4; ++j) {
            float mx = -1e30f;
#pragma unroll
            for (int kt = 0; kt < 2; ++kt) {
                float v = (kt * 64 + lane < m) ? va[j][kt] : -1e30f;
                va[j][kt] = v;
                mx = fmaxf(mx, v);
            }
#pragma unroll
            for (int off = 32; off; off >>= 1) mx = fmaxf(mx, __shfl_xor(mx, off));
            float sum = 0.f;
#pragma unroll
            for (int kt = 0; kt < 2; ++kt) {
                float e = (va[j][kt] <= -1e29f) ? 0.f : __expf(va[j][kt] - mx);
                va[j][kt] = e;
                sum += e;
            }
#pragma unroll
            for (int off = 32; off; off >>= 1) sum += __shfl_xor(sum, off);
            float is = 1.f / sum;
            va[j][0] *= is; va[j][1] *= is;
        }

        float2 po[4];
#pragma unroll
        for (int j = 0; j < 4; ++j) po[j] = make_float2(0.f, 0.f);
#pragma unroll
        for (int kt = 0; kt < 2; ++kt) {
            if (kt * 64 < m) {
                const int wn = min(64, m - kt * 64);
                for (int w = 0; w < wn; ++w) {
                    float2 kv = *(const float2*)(cvb + s_coff[kt * 64 + w] + lane * 8);
                    float a0 = rdlane(va[0][kt], w);
                    float a1 = rdlane(va[1][kt], w);
                    float a2 = rdlane(va[2][kt], w);
                    float a3 = rdlane(va[3][kt], w);
                    po[0].x += a0 * kv.x; po[0].y += a0 * kv.y;
                    po[1].x += a1 * kv.x; po[1].y += a1 * kv.y;
                    po[2].x += a2 * kv.x; po[2].y += a2 * kv.y;
                    po[3].x += a3 * kv.x; po[3].y += a3 * kv.y;
                }
            }
        }
#pragma unroll
        for (int j = 0; j < 4; ++j)
            *(float2*)&outp[orow + (size_t)j * 128 + lane * 2] =
                make_float2(po[j].x * invn, po[j].y * invn);
    } else {
        // -------- m > 128 (rare) : 4 w-tiles, same pipeline --------
        int wreg[4];
#pragma unroll
        for (int kt = 0; kt < 4; ++kt) wreg[kt] = s_widx[min(kt * 64 + lane, mc)];
        float va[4][4];
#pragma unroll
        for (int j = 0; j < 4; ++j)
#pragma unroll
            for (int k = 0; k < 4; ++k) va[j][k] = 0.f;

#pragma unroll 2
        for (int nc = 0; nc < 32; ++nc) {
            uint2 h0 = *(const uint2*)&s_hq[(nc * 200 + wreg[0]) << 2];
            uint2 h1 = *(const uint2*)&s_hq[(nc * 200 + wreg[1]) << 2];
            uint2 h2 = *(const uint2*)&s_hq[(nc * 200 + wreg[2]) << 2];
            uint2 h3 = *(const uint2*)&s_hq[(nc * 200 + wreg[3]) << 2];
            float h0a = bf_lo(h0.x), h0b = bf_hi(h0.x), h0c = bf_lo(h0.y), h0d = bf_hi(h0.y);
            float h1a = bf_lo(h1.x), h1b = bf_hi(h1.x), h1c = bf_lo(h1.y), h1d = bf_hi(h1.y);
            float h2a = bf_lo(h2.x), h2b = bf_hi(h2.x), h2c = bf_lo(h2.y), h2d = bf_hi(h2.y);
            float h3a = bf_lo(h3.x), h3b = bf_hi(h3.x), h3c = bf_lo(h3.y), h3d = bf_hi(h3.y);
            float4 hwv = hw4p[nc];
#pragma unroll
            for (int jt = 0; jt < 4; ++jt) {
                uint2 pu = *(const uint2*)&s_hp[(t0 + jt) * 128 + nc * 4];
                float pa = bf_lo(pu.x), pb = bf_hi(pu.x), pc = bf_lo(pu.y), pd = bf_hi(pu.y);
                SCS(jt, 0, h0a, h0b, h0c, h0d, pa, pb, pc, pd)
                SCS(jt, 1, h1a, h1b, h1c, h1d, pa, pb, pc, pd)
                SCS(jt, 2, h2a, h2b, h2c, h2d, pa, pb, pc, pd)
                SCS(jt, 3, h3a, h3b, h3c, h3d, pa, pb, pc, pd)
            }
        }

#pragma unroll
        for (int j = 0; j < 4; ++j) {
            float mx = -1e30f;
#pragma unroll
            for (int kt = 0; kt < 4; ++kt) {
                float v = (kt * 64 + lane < m) ? va[j][kt] : -1e30f;
                va[j][kt] = v;
                mx = fmaxf(mx, v);
            }
#pragma unroll
            for (int off = 32; off; off >>= 1) mx = fmaxf(mx, __shfl_xor(mx, off));
            float sum = 0.f;
#pragma unroll
            for (int kt = 0; kt < 4; ++kt) {
                float e = (va[j][kt] <= -1e29f) ? 0.f : __expf(va[j][kt] - mx);
                va[j][kt] = e;
                sum += e;
            }
#pragma unroll
            for (int off = 32; off; off >>= 1) sum += __shfl_xor(sum, off);
            float is = 1.f / sum;
#pragma unroll
            for (int kt = 0; kt < 4; ++kt) va[j][kt] *= is;
        }

        float2 po[4];
#pragma unroll
        for (int j = 0; j < 4; ++j) po[j] = make_float2(0.f, 0.f);
#pragma unroll
        for (int kt = 0; kt < 4; ++kt) {
            if (kt * 64 < m) {
                const int wn = min(64, m - kt * 64);
                for (int w = 0; w < wn; ++w) {
                    float2 kv = *(const float2*)(cvb + s_coff[kt * 64 + w] + lane * 8);
                    float a0 = rdlane(va[0][kt], w);
                    float a1 = rdlane(va[1][kt], w);
                    float a2 = rdlane(va[2][kt], w);
                    float a3 = rdlane(va[3][kt], w);
                    po[0].x += a0 * kv.x; po[0].y += a0 * kv.y;
                    po[1].x += a1 * kv.x; po[1].y += a1 * kv.y;
                    po[2].x += a2 * kv.x; po[2].y += a2 * kv.y;
                    po[3].x += a3 * kv.x; po[3].y += a3 * kv.y;
                }
            }
        }
#pragma unroll
        for (int j = 0; j < 4; ++j)
            *(float2*)&outp[orow + (size_t)j * 128 + lane * 2] =
                make_float2(po[j].x * invn, po[j].y * invn);
    }
#undef SCS
}

// ---------------------------------------------------------------------------
extern "C" void kernel_launch(void* const* d_in, const int* in_sizes, int n_in,
                              void* d_out, int out_size, void* d_ws, size_t ws_size,
                              hipStream_t stream) {
    const float* tvecs = (const float*)d_in[0];
    const float* cvecs = (const float*)d_in[1];
    const float* Ww    = (const float*)d_in[2];
    const float* Wb    = (const float*)d_in[3];
    const float* hw    = (const float*)d_in[4];
    // d_in[5] = h_b : unused (softmax shift-invariance)
    const int* titems  = (const int*)d_in[6];
    const int* citems  = (const int*)d_in[7];
    const void* mask   = d_in[8];
    float* out         = (float*)d_out;

    if (ws_size < 70000) return;      // flag(256B) + Wb16(64KB)

    int*    flag = (int*)d_ws;
    ushort* Wb16 = (ushort*)((float*)d_ws + 64);

    prep_kernel<<<129, 256, 0, stream>>>(Ww, Wb16, (const int*)mask, flag);
    attn_kernel<<<BB * 2, 512, 0, stream>>>(tvecs, cvecs, Wb16, Wb, hw,
                                            titems, citems, mask, flag, out);
}